// Round 3
// baseline (4531.190 us; speedup 1.0000x reference)
//
#include <hip/hip_runtime.h>

#define DI __device__ __forceinline__
#define NSAMP 65536

DI float frcp(float x){ return __builtin_amdgcn_rcpf(x); }
DI float frsq(float x){ return __builtin_amdgcn_rsqf(x); }
DI float sigmf(float x){ return frcp(1.f + __expf(-x)); }
DI float tanhf_(float x){ return 1.f - 2.f*frcp(__expf(2.f*x) + 1.f); }

struct Params {
  const float* __restrict__ x;
  const float* __restrict__ xT;    // SoA packed features [320][NSAMP] (ws)
  const float* __restrict__ w1ft;  // W1f transposed [108][32] (ws tail)
  const float* __restrict__ Wih0; const float* __restrict__ Whh0;
  const float* __restrict__ bih0; const float* __restrict__ bhh0;
  const float* __restrict__ Wih1; const float* __restrict__ Whh1;
  const float* __restrict__ bih1; const float* __restrict__ bhh1;
  const float* __restrict__ fcW;  const float* __restrict__ fcb;
  const float* __restrict__ W2;   const float* __restrict__ b2;
  const float* __restrict__ g2;   const float* __restrict__ be2;
  const float* __restrict__ W3;   const float* __restrict__ b3;
  const float* __restrict__ g3;   const float* __restrict__ be3;
  const float* __restrict__ W1f;  const float* __restrict__ b1f;
  const float* __restrict__ g1f;  const float* __restrict__ be1f;
  const float* __restrict__ W2f;  const float* __restrict__ b2f;
  const float* __restrict__ g2f;  const float* __restrict__ be2f;
  const float* __restrict__ W3f;  const float* __restrict__ b3f;
  const float* __restrict__ g3f;  const float* __restrict__ be3f;
  float* __restrict__ out;
};

// feature accessors: f = r*102+c for csi (c may exceed 101 into harmless
// in-bounds pad region, value masked by caller), pos k -> 306+k.
template<bool SOA>
DI float ldcsi(const float* __restrict__ base, int b, int r, int c){
  if constexpr(SOA) return base[(size_t)(r*102 + c)*NSAMP + b];
  else              return base[(size_t)b*348 + r*116 + 1 + c];
}
template<bool SOA>
DI float ldpos(const float* __restrict__ base, int b, int k){
  if constexpr(SOA) return base[(size_t)(306 + k)*NSAMP + b];
  else              return base[(size_t)b*348 + 220 + k];
}

// ---------- pack kernel: x (AoS) -> xT (SoA), plus W1f transpose ----------
__global__ __launch_bounds__(256,1) void pack_kernel(const float* __restrict__ x,
                                                     float* __restrict__ xT,
                                                     const float* __restrict__ W1f,
                                                     float* __restrict__ w1ft){
  __shared__ float s[64*349];
  const int b0 = blockIdx.x*64;
  const float4* src = reinterpret_cast<const float4*>(x + (size_t)b0*348);
  for(int i=threadIdx.x; i<64*87; i+=256){
    float4 v = src[i];
    int smp = i/87; int off = (i - smp*87)*4;
    float* d = &s[smp*349 + off];
    d[0]=v.x; d[1]=v.y; d[2]=v.z; d[3]=v.w;
  }
  __syncthreads();
  for(int i=threadIdx.x; i<320*64; i+=256){
    int f = i>>6; int sI = i&63;
    int off;
    if(f < 306){ int r = f/102; off = r*14 + 1 + f; }
    else if(f < 318) off = 220 + (f-306);
    else off = 0;
    xT[(size_t)f*NSAMP + b0 + sI] = s[sI*349 + off];
  }
  if(blockIdx.x == 0){
    for(int i=threadIdx.x; i<108*32; i+=256){
      int w = i>>5, j = i&31;
      w1ft[w*32 + j] = W1f[j*108 + w];
    }
  }
}

// quad allgather: each lane of a 4-lane group holds 8 values (block q*8..q*8+7);
// produce full 32 in every lane. Static register indices throughout.
DI void allgather32(const float* mine8, float* full32, int q){
  const bool q1 = (q & 1) != 0;
  const bool q2 = (q & 2) != 0;
  float a[16];
  #pragma unroll
  for(int i=0;i<8;i++){
    float o = __shfl_xor(mine8[i], 1);
    a[i]    = q1 ? o : mine8[i];
    a[8+i]  = q1 ? mine8[i] : o;
  }
  #pragma unroll
  for(int i=0;i<16;i++){
    float o = __shfl_xor(a[i], 2);
    full32[i]    = q2 ? o : a[i];
    full32[16+i] = q2 ? a[i] : o;
  }
}
DI float qreduce(float v){
  v += __shfl_xor(v, 1);
  v += __shfl_xor(v, 2);
  return v;
}

// one LSTM cell step for 8 hidden units (j = J0..J0+7) of one sample
template<int IN>
DI void lstm_step8(const float* __restrict__ Wih, const float* __restrict__ Whh,
                   const float* __restrict__ bih, const float* __restrict__ bhh,
                   int J0, const float* xin, const float* hin32,
                   float* c8, float* h8){
  #pragma unroll
  for(int jj=0;jj<8;jj++){
    const int j = J0 + jj;
    float ai = bih[j]    + bhh[j];
    float af = bih[32+j] + bhh[32+j];
    float ag = bih[64+j] + bhh[64+j];
    float ao = bih[96+j] + bhh[96+j];
    #pragma unroll
    for(int k=0;k<IN;k++){
      float xv = xin[k];
      ai += xv*Wih[j*IN+k];
      af += xv*Wih[(32+j)*IN+k];
      ag += xv*Wih[(64+j)*IN+k];
      ao += xv*Wih[(96+j)*IN+k];
    }
    #pragma unroll
    for(int k=0;k<32;k++){
      float hv = hin32[k];
      ai += hv*Whh[j*32+k];
      af += hv*Whh[(32+j)*32+k];
      ag += hv*Whh[(64+j)*32+k];
      ao += hv*Whh[(96+j)*32+k];
    }
    float cc = sigmf(af)*c8[jj] + sigmf(ai)*tanhf_(ag);
    c8[jj] = cc;
    h8[jj] = sigmf(ao)*tanhf_(cc);
  }
}

// 4 threads (a lane quad) cooperate on one sample. 128 thr = 32 samples/block.
template<bool SOA>
__global__ __launch_bounds__(128,3) void csnet_main(Params p){
  const int tid  = threadIdx.x;
  const int q    = tid & 3;
  const int sloc = tid >> 2;                  // sample within block, 0..31
  const int b    = blockIdx.x*32 + sloc;
  const float* __restrict__ xb = SOA ? p.xT : p.x;
  __shared__ float sbuf[32*103];
  float* my = &sbuf[sloc*103];
  const int J0    = q*8;                      // hidden-unit block
  const int cbase = q*26;                     // conv/f3 column block
  const int ncol  = (q==3) ? 24 : 26;

  // ---------------- LSTM (2 layers, 4 steps), 8 units/thread ----------------
  float h0f[32], h1f[32], c0[8], c1[8];
  #pragma unroll
  for(int j=0;j<32;j++){ h0f[j]=0.f; h1f[j]=0.f; }
  #pragma unroll
  for(int j=0;j<8;j++){ c0[j]=0.f; c1[j]=0.f; }
  #pragma unroll 1
  for(int t=0;t<4;t++){
    float xt[3];
    #pragma unroll
    for(int d=0;d<3;d++) xt[d] = ldpos<SOA>(xb, b, t*3+d);
    float h8a[8], h8b[8];
    lstm_step8<3 >(p.Wih0,p.Whh0,p.bih0,p.bhh0, J0, xt,  h0f, c0, h8a);
    allgather32(h8a, h0f, q);
    lstm_step8<32>(p.Wih1,p.Whh1,p.bih1,p.bhh1, J0, h0f, h1f, c1, h8b);
    allgather32(h8b, h1f, q);
  }
  // pos_p / vel — uniform weights, computed redundantly per lane
  float pp[3], vel[3];
  #pragma unroll
  for(int d=0;d<3;d++){
    float a = p.fcb[d];
    #pragma unroll
    for(int j=0;j<32;j++) a += h1f[j]*p.fcW[d*32+j];
    pp[d]  = a;
    vel[d] = (a - ldpos<SOA>(xb, b, 9+d))*10.f;
  }

  // ---------------- conv2 pass 1: LN stats, 26 cols/thread ----------------
  float s1 = 0.f, s2 = 0.f;
  {
    float u0[3],u1[3],u2[3],u3[3],u4[3];
    #pragma unroll
    for(int r=0;r<3;r++){
      int pc;
      pc = cbase-2; u0[r] = (pc>=0) ? ldcsi<SOA>(xb,b,r,pc<0?0:pc) : 0.f;
      pc = cbase-1; u1[r] = (pc>=0) ? ldcsi<SOA>(xb,b,r,pc<0?0:pc) : 0.f;
      u2[r] = ldcsi<SOA>(xb,b,r,cbase);
      u3[r] = ldcsi<SOA>(xb,b,r,cbase+1);
      u4[r] = ldcsi<SOA>(xb,b,r,cbase+2);
    }
    #pragma unroll 2
    for(int i=0;i<26;i++){
      float msk = (q==3 && i>=24) ? 0.f : 1.f;
      #pragma unroll
      for(int o=0;o<4;o++){
        const float* Wo = &p.W2[o*15];
        float s = p.b2[o];
        #pragma unroll
        for(int r=0;r<3;r++)
          s += u0[r]*Wo[r*5+0]+u1[r]*Wo[r*5+1]+u2[r]*Wo[r*5+2]+u3[r]*Wo[r*5+3]+u4[r]*Wo[r*5+4];
        s1 += msk*s; s2 += msk*s*s;
      }
      int pnext = cbase + i + 3;                 // next col entering window
      #pragma unroll
      for(int r=0;r<3;r++){
        float nv = ldcsi<SOA>(xb,b,r,pnext);     // in-bounds even past 101
        nv = (pnext <= 101) ? nv : 0.f;          // zero-pad
        u0[r]=u1[r]; u1[r]=u2[r]; u2[r]=u3[r]; u3[r]=u4[r]; u4[r]=nv;
      }
    }
  }
  float m2  = qreduce(s1)*(1.f/408.f);
  float va2 = qreduce(s2)*(1.f/408.f) - m2*m2;
  float rs2 = frsq(va2 + 1e-5f);

  // ---------- conv2 pass 2 (recompute) + LN/relu + cv3 -> my[w] ----------
  float w3v[4];
  #pragma unroll
  for(int o=0;o<4;o++) w3v[o] = p.W3[o];
  float b3v = p.b3[0];
  float s31=0.f, s32=0.f;
  {
    float u0[3],u1[3],u2[3],u3[3],u4[3];
    #pragma unroll
    for(int r=0;r<3;r++){
      int pc;
      pc = cbase-2; u0[r] = (pc>=0) ? ldcsi<SOA>(xb,b,r,pc<0?0:pc) : 0.f;
      pc = cbase-1; u1[r] = (pc>=0) ? ldcsi<SOA>(xb,b,r,pc<0?0:pc) : 0.f;
      u2[r] = ldcsi<SOA>(xb,b,r,cbase);
      u3[r] = ldcsi<SOA>(xb,b,r,cbase+1);
      u4[r] = ldcsi<SOA>(xb,b,r,cbase+2);
    }
    #pragma unroll 2
    for(int i=0;i<26;i++){
      const int w = cbase + i;
      float msk = (q==3 && i>=24) ? 0.f : 1.f;
      float o3 = b3v;
      #pragma unroll
      for(int o=0;o<4;o++){
        const float* Wo = &p.W2[o*15];
        float s = p.b2[o];
        #pragma unroll
        for(int r=0;r<3;r++)
          s += u0[r]*Wo[r*5+0]+u1[r]*Wo[r*5+1]+u2[r]*Wo[r*5+2]+u3[r]*Wo[r*5+3]+u4[r]*Wo[r*5+4];
        int wc = (w <= 101) ? w : 101;           // keep param reads in-bounds
        float nv = (s - m2)*rs2*p.g2[o*102+wc] + p.be2[o*102+wc];
        o3 += fmaxf(nv, 0.f)*w3v[o];
      }
      s31 += msk*o3; s32 += msk*o3*o3;
      if(i < ncol) my[w] = o3;
      int pnext = cbase + i + 3;
      #pragma unroll
      for(int r=0;r<3;r++){
        float nv = ldcsi<SOA>(xb,b,r,pnext);
        nv = (pnext <= 101) ? nv : 0.f;
        u0[r]=u1[r]; u1[r]=u2[r]; u2[r]=u3[r]; u3[r]=u4[r]; u4[r]=nv;
      }
    }
  }
  float m3  = qreduce(s31)*(1.f/102.f);
  float va3 = qreduce(s32)*(1.f/102.f) - m3*m3;
  float rs3 = frsq(va3 + 1e-5f);

  // ---------------- f1: 108 -> 32 (8 outputs/thread), LN, relu ----------------
  float a1[8];
  #pragma unroll
  for(int jj=0;jj<8;jj++) a1[jj] = p.b1f[J0+jj];
  #pragma unroll 2
  for(int w=0; w<102; ++w){
    float v = (my[w]-m3)*rs3*p.g3[w] + p.be3[w];
    v = fmaxf(v, 0.f);
    const float* wr = SOA ? &p.w1ft[w*32+J0] : nullptr;
    #pragma unroll
    for(int jj=0;jj<8;jj++)
      a1[jj] += v * (SOA ? wr[jj] : p.W1f[(J0+jj)*108+w]);
  }
  #pragma unroll
  for(int d=0;d<3;d++){
    #pragma unroll
    for(int jj=0;jj<8;jj++){
      a1[jj] += pp[d]  * (SOA ? p.w1ft[(102+d)*32+J0+jj] : p.W1f[(J0+jj)*108+102+d]);
      a1[jj] += vel[d] * (SOA ? p.w1ft[(105+d)*32+J0+jj] : p.W1f[(J0+jj)*108+105+d]);
    }
  }
  {
    float s=0.f, qq=0.f;
    #pragma unroll
    for(int jj=0;jj<8;jj++){ s += a1[jj]; qq += a1[jj]*a1[jj]; }
    float m  = qreduce(s)*(1.f/32.f);
    float va = qreduce(qq)*(1.f/32.f) - m*m;
    float rs = frsq(va + 1e-5f);
    #pragma unroll
    for(int jj=0;jj<8;jj++)
      a1[jj] = fmaxf((a1[jj]-m)*rs*p.g1f[J0+jj] + p.be1f[J0+jj], 0.f);
  }

  // ---------------- f2: 32 -> 32 (8 outputs/thread), LN, relu ----------------
  float a1f[32];
  allgather32(a1, a1f, q);
  float a2[8];
  #pragma unroll
  for(int jj=0;jj<8;jj++){
    const int j = J0 + jj;
    float a = p.b2f[j];
    #pragma unroll
    for(int k=0;k<32;k++) a += a1f[k]*p.W2f[j*32+k];
    a2[jj] = a;
  }
  {
    float s=0.f, qq=0.f;
    #pragma unroll
    for(int jj=0;jj<8;jj++){ s += a2[jj]; qq += a2[jj]*a2[jj]; }
    float m  = qreduce(s)*(1.f/32.f);
    float va = qreduce(qq)*(1.f/32.f) - m*m;
    float rs = frsq(va + 1e-5f);
    #pragma unroll
    for(int jj=0;jj<8;jj++)
      a2[jj] = fmaxf((a2[jj]-m)*rs*p.g2f[J0+jj] + p.be2f[J0+jj], 0.f);
  }

  // ---------------- f3: 32 -> 102 (26 cols/thread), LN, sigmoid ----------------
  float a2f[32];
  allgather32(a2, a2f, q);
  float fw[26];
  float t1=0.f, t2=0.f;
  #pragma unroll
  for(int i=0;i<26;i++){
    const int w  = cbase + i;
    const int wc = (w <= 101) ? w : 101;
    float a = p.b3f[wc];
    #pragma unroll
    for(int j=0;j<32;j++) a += a2f[j]*p.W3f[wc*32+j];
    float msk = (q==3 && i>=24) ? 0.f : 1.f;
    t1 += msk*a; t2 += msk*a*a;
    fw[i] = a;
  }
  float mf  = qreduce(t1)*(1.f/102.f);
  float vaf = qreduce(t2)*(1.f/102.f) - mf*mf;
  float rsf = frsq(vaf + 1e-5f);
  #pragma unroll
  for(int i=0;i<26;i++){
    const int w = cbase + i;
    if(i < ncol){
      float u = (fw[i]-mf)*rsf*p.g3f[w] + p.be3f[w];
      my[w] = sigmf(u);
    }
  }
  __syncthreads();

  // ---------------- coalesced float4 store: 3264 floats/block ----------------
  float* op = p.out + (size_t)blockIdx.x*3264;
  #pragma unroll 1
  for(int m=0;m<7;m++){
    int i4 = tid + 128*m;
    if(i4 < 816){
      int i0 = i4*4;
      float4 v;
      #pragma unroll
      for(int e=0;e<4;e++){
        int idx = i0 + e;
        int sm = idx/102;
        int wd = idx - sm*102;
        ((float*)&v)[e] = sbuf[sm*103 + wd];
      }
      *reinterpret_cast<float4*>(op + i0) = v;
    }
  }
}

extern "C" void kernel_launch(void* const* d_in, const int* in_sizes, int n_in,
                              void* d_out, int out_size, void* d_ws, size_t ws_size,
                              hipStream_t stream) {
  (void)in_sizes; (void)n_in; (void)out_size;
  Params p;
  p.x    = (const float*)d_in[0];
  p.Wih0 = (const float*)d_in[1];  p.Whh0 = (const float*)d_in[2];
  p.bih0 = (const float*)d_in[3];  p.bhh0 = (const float*)d_in[4];
  p.Wih1 = (const float*)d_in[5];  p.Whh1 = (const float*)d_in[6];
  p.bih1 = (const float*)d_in[7];  p.bhh1 = (const float*)d_in[8];
  p.fcW  = (const float*)d_in[9];  p.fcb  = (const float*)d_in[10];
  p.W2   = (const float*)d_in[11]; p.b2   = (const float*)d_in[12];
  p.g2   = (const float*)d_in[13]; p.be2  = (const float*)d_in[14];
  p.W3   = (const float*)d_in[15]; p.b3   = (const float*)d_in[16];
  p.g3   = (const float*)d_in[17]; p.be3  = (const float*)d_in[18];
  p.W1f  = (const float*)d_in[19]; p.b1f  = (const float*)d_in[20];
  p.g1f  = (const float*)d_in[21]; p.be1f = (const float*)d_in[22];
  p.W2f  = (const float*)d_in[23]; p.b2f  = (const float*)d_in[24];
  p.g2f  = (const float*)d_in[25]; p.be2f = (const float*)d_in[26];
  p.W3f  = (const float*)d_in[27]; p.b3f  = (const float*)d_in[28];
  p.g3f  = (const float*)d_in[29]; p.be3f = (const float*)d_in[30];
  p.out  = (float*)d_out;

  const size_t need = ((size_t)320*NSAMP + 108*32)*sizeof(float);
  if(ws_size >= need){
    float* xT   = (float*)d_ws;
    float* w1ft = xT + (size_t)320*NSAMP;
    p.xT = xT; p.w1ft = w1ft;
    pack_kernel<<<NSAMP/64, 256, 0, stream>>>(p.x, xT, p.W1f, w1ft);
    csnet_main<true><<<NSAMP/32, 128, 0, stream>>>(p);
  } else {
    p.xT = nullptr; p.w1ft = nullptr;
    csnet_main<false><<<NSAMP/32, 128, 0, stream>>>(p);
  }
}